// Round 4
// baseline (127.183 us; speedup 1.0000x reference)
//
#include <hip/hip_runtime.h>
#include <hip/hip_bf16.h>
#include <stdint.h>

// B=32, C=256, H=W=32, 3x3 conv pad 1 -> implicit GEMM in INT8.
// M = 32768 (b,h,w), N = 256 (co), K = 2304; k = (kh*3+kw)*256 + ci.
// Two dispatches: (1) merged quant kernel (x -> int8 padded NHWC; w -> ternary
// int8 in MFMA fragment order), (2) GEMM.
//
// R4: GEMM re-blocked 128x128 -> 256m x 128n per block (grid 256 = 1 block/CU,
// 87KB LDS). 8 waves each own 32m x 128n (one h-row, 8 n-frags, 2 m-frags of
// 16x16x64 i8 -- fragment layouts and wq format IDENTICAL to the proven R0
// kernel). A-LDS ds_read traffic /4 (604->151 MB, was the top pipe at 11.6us);
// all 8 waves stream the same 16KB/kt of B -> L1 dedup (L2 traffic 75MB).
// MFMA is now the top pipe (9.8us floor). Staging split: rows 0..7 (68KB,
// needed by kh=0) -> barrier -> kt 0..11 while rows 8..9 stream in -> barrier
// -> kt 12..35.

typedef int i32x4 __attribute__((ext_vector_type(4)));
typedef float f32x4 __attribute__((ext_vector_type(4)));

__device__ __forceinline__ void gload_lds16(const void* g, const void* lds) {
    __builtin_amdgcn_global_load_lds(
        (const __attribute__((address_space(1))) unsigned int*)(uintptr_t)g,
        (__attribute__((address_space(3))) unsigned int*)(uintptr_t)lds,
        16, 0, 0);
}

// Merged quantization (R3 version, unchanged). Blocks 0..1087: x-row ->
// int8 padded NHWC [b][34][34][ci], borders zeroed. Blocks 1088..1343:
// weight channel co -> ternary int8, MFMA-fragment order
// B'[(co>>4)][kt][kq][co&15][j], elem = Wq[co][k=kt*64+kq*16+j].
__global__ __launch_bounds__(256) void quant_kernel(
    const float* __restrict__ x, const float* __restrict__ w,
    signed char* __restrict__ xpad, signed char* __restrict__ wq)
{
    __shared__ signed char tile[32 * 272];
    const int t = threadIdx.x;
    const int blk = blockIdx.x;

    if (blk >= 1088) {                        // ---- weight path ----
        const int co = blk - 1088;
        signed char* wt = tile;               // reuse as [khkw*256 + ci]
#pragma unroll
        for (int p = 0; p < 9; ++p) {
            const int idx = p * 256 + t;      // = ci*9 + khkw
            const float v = w[co * 2304 + idx];
            const int ci = idx / 9;
            const int khkw = idx - 9 * ci;
            const float q = fminf(fmaxf(rintf(v), -1.f), 1.f);
            wt[khkw * 256 + ci] = (signed char)(int)q;
        }
        __syncthreads();
        if (t < 144) {                        // t = kt*4 + kq
            const int kt = t >> 2, kq = t & 3;
            const uint4 v = *(const uint4*)(wt + t * 16);
            *(uint4*)(wq + ((size_t)((co >> 4) * 36 + kt) << 10) + kq * 256 + (co & 15) * 16) = v;
        }
        return;
    }

    // ---- x path ----
    const int b = blk / 34;
    const int hp = blk % 34;
    signed char* rowbase = xpad + (size_t)((b * 34 + hp) * 34) * 256;
    const uint4 z = {0u, 0u, 0u, 0u};
    if (hp == 0 || hp == 33) {                // whole padded row = zeros
        for (int i = t; i < 544; i += 256) *(uint4*)(rowbase + i * 16) = z;
        return;
    }
    const int h = hp - 1;
    const float* xb = x + ((size_t)(b * 256) * 32 + h) * 32;   // + ci*1024 + w

#pragma unroll
    for (int q2 = 0; q2 < 2; ++q2) {
        const int beta = q2 * 256 + t;
        const int cib = beta >> 3;            // 0..63  (ci0 = 4*cib)
        const int w4 = beta & 7;              // 0..7   (w = w4*4 .. +3)
        unsigned row[4];
#pragma unroll
        for (int j = 0; j < 4; ++j) {
            const f32x4 v = *(const f32x4*)(xb + (size_t)(cib * 4 + j) * 1024 + w4 * 4);
            unsigned p = 0;
#pragma unroll
            for (int k = 0; k < 4; ++k) {
                const float q = fminf(fmaxf(rintf(__fmul_rn(v[k], 128.f)), -128.f), 127.f);
                p |= ((unsigned)(unsigned char)(signed char)(int)q) << (8 * k);
            }
            row[j] = p;
        }
        const unsigned ab_lo = __builtin_amdgcn_perm(row[1], row[0], 0x05010400u);
        const unsigned ab_hi = __builtin_amdgcn_perm(row[1], row[0], 0x07030602u);
        const unsigned cd_lo = __builtin_amdgcn_perm(row[3], row[2], 0x05010400u);
        const unsigned cd_hi = __builtin_amdgcn_perm(row[3], row[2], 0x07030602u);
        unsigned col[4];
        col[0] = __builtin_amdgcn_perm(cd_lo, ab_lo, 0x05040100u);
        col[1] = __builtin_amdgcn_perm(cd_lo, ab_lo, 0x07060302u);
        col[2] = __builtin_amdgcn_perm(cd_hi, ab_hi, 0x05040100u);
        col[3] = __builtin_amdgcn_perm(cd_hi, ab_hi, 0x07060302u);
#pragma unroll
        for (int r = 0; r < 4; ++r)
            *(unsigned*)(tile + (w4 * 4 + r) * 272 + cib * 4) = col[r];
    }
    __syncthreads();
#pragma unroll
    for (int q = 0; q < 2; ++q) {             // interior: 16B/lane, coalesced
        const int wp = q * 16 + (t >> 4);
        const int ci16 = (t & 15) * 16;
        uint4 v = *(const uint4*)(tile + wp * 272 + ci16);
        *(uint4*)(rowbase + (size_t)(wp + 1) * 256 + ci16) = v;
    }
    if (t < 32) {                             // zero border cols wp=0,33
        const int wp = (t >> 4) * 33;
        *(uint4*)(rowbase + (size_t)wp * 256 + (t & 15) * 16) = z;
    }
}

// GEMM: grid 256 (128 m-tiles x 2 n-tiles), 512 threads = 8 waves.
// Block = 256m x 128n. Wave wv owns h-row h0+wv: 32m x 128n =
// 2 m-frags x 8 n-frags of 16x16x64 i8. LDS: A halo, 10 rows x 34 x 256 =
// 87,040 B, xor-swizzled chunks. 1 block/CU, 2 waves/SIMD.
__global__ __launch_bounds__(512, 2) void conv_gemm_kernel(
    const signed char* __restrict__ xpad, const signed char* __restrict__ wqm,
    const float* __restrict__ gamma, const float* __restrict__ beta,
    const float* __restrict__ mean, const float* __restrict__ var,
    float* __restrict__ out)
{
    __shared__ signed char As[10 * 34 * 256];  // [r=hh*34+wp][chunk ^ (r&15)][16]

    const int tid = threadIdx.x;
    const int wv = tid >> 6;                   // 0..7 = h-row within block
    const int lane = tid & 63;
    const int l16 = lane & 15;
    const int l4 = lane >> 4;

    const int mt = blockIdx.x >> 1;            // 0..127
    const int n0 = (blockIdx.x & 1) * 128;
    const int b = mt >> 2;                     // 0..31
    const int h0 = (mt & 3) * 8;               // 0,8,16,24

    // ---- stage A halo: padded rows h0..h0+9, all 34 wp, all 256 ci ----
    const signed char* xbase = xpad + (size_t)(b * 34 + h0) * 34 * 256;
    // phase 1: rows 0..7 (shots 0..67) -- needed by kh=0 (kt 0..11)
#pragma unroll
    for (int p = 0; p < 9; ++p) {
        const int i = p * 8 + wv;
        if (i < 68) {
            const int d = i * 64 + lane;
            const int r = d >> 4;
            const int c = d & 15;
            gload_lds16(xbase + r * 256 + ((c ^ (r & 15)) << 4), As + i * 1024);
        }
    }
    __syncthreads();
    // phase 2: rows 8..9 (shots 68..84), async -- completed by 2nd barrier
#pragma unroll
    for (int p = 0; p < 3; ++p) {
        const int i = 68 + p * 8 + wv;
        if (i < 85) {
            const int d = i * 64 + lane;
            const int r = d >> 4;
            const int c = d & 15;
            gload_lds16(xbase + r * 256 + ((c ^ (r & 15)) << 4), As + i * 1024);
        }
    }

    int r0[2];
#pragma unroll
    for (int i = 0; i < 2; ++i)
        r0[i] = wv * 34 + i * 16 + l16;        // + kh*34 + kw at load time

    const signed char* bp[8];
#pragma unroll
    for (int j = 0; j < 8; ++j)
        bp[j] = wqm + (((size_t)((n0 >> 4) + j) * 36) << 10) + lane * 16;

    i32x4 acc[2][8];
#pragma unroll
    for (int i = 0; i < 2; i++)
#pragma unroll
        for (int j = 0; j < 8; j++) acc[i][j] = (i32x4){0, 0, 0, 0};

    i32x4 aP[2][2], bP[2][8];

#define LOAD_B(kt, dst) { _Pragma("unroll") \
                          for (int j = 0; j < 8; ++j) \
                              dst[j] = *(const i32x4*)(bp[j] + (kt) * 1024); }
#define LOAD_A(kt, dst) { const int khkw = (kt) >> 2; \
                          const int kh = khkw / 3; \
                          const int kw = khkw - 3 * kh; \
                          const int roff = kh * 34 + kw; \
                          const int cb = ((kt) & 3) * 4 + l4; \
                          _Pragma("unroll") \
                          for (int i = 0; i < 2; ++i) { \
                              const int r = r0[i] + roff; \
                              dst[i] = *(const i32x4*)(As + r * 256 + ((cb ^ (r & 15)) << 4)); \
                          } }
#define MFMA(af, bf) { _Pragma("unroll") \
                       for (int i = 0; i < 2; ++i) \
                           _Pragma("unroll") \
                           for (int j = 0; j < 8; ++j) \
                               acc[i][j] = __builtin_amdgcn_mfma_i32_16x16x64_i8(af[i], bf[j], acc[i][j], 0, 0, 0); }

    LOAD_B(0, bP[0])
    LOAD_A(0, aP[0])
    // kt 0..10: standard distance-1 double buffer (all reads rows 0..7)
#pragma unroll
    for (int kt = 0; kt < 11; ++kt) {
        const int cur = kt & 1, nxt = cur ^ 1;
        LOAD_B(kt + 1, bP[nxt])
        LOAD_A(kt + 1, aP[nxt])
        MFMA(aP[cur], bP[cur])
    }
    // kt = 11: prefetch B(12) only; A(12) needs row 8 -> after barrier
    LOAD_B(12, bP[0])
    MFMA(aP[1], bP[1])
    __syncthreads();                           // rows 8..9 now resident
    LOAD_A(12, aP[0])
#pragma unroll
    for (int kt = 12; kt < 36; ++kt) {
        const int cur = kt & 1, nxt = cur ^ 1;
        if (kt + 1 < 36) { LOAD_B(kt + 1, bP[nxt]) LOAD_A(kt + 1, aP[nxt]) }
        MFMA(aP[cur], bP[cur])
    }

    // ---- epilogue: C/D col = l16 (n), row = l4*4 + r (m within frag) ----
    const int h = h0 + wv;
#pragma unroll
    for (int j = 0; j < 8; ++j) {
        const int co = n0 + j * 16 + l16;
        const float iv = __fdiv_rn(gamma[co], __fsqrt_rn(__fadd_rn(var[co], 1e-4f)));
        const float bias = __fsub_rn(beta[co], __fmul_rn(mean[co], iv));
#pragma unroll
        for (int i = 0; i < 2; ++i) {
            const int w = i * 16 + l4 * 4;
            f32x4 v;
#pragma unroll
            for (int r = 0; r < 4; r++) {
                const float y = __fmul_rn((float)acc[i][j][r], 0.0078125f);  // exact pow2
                const float t = __fadd_rn(__fmul_rn(y, iv), bias);           // no FMA: match np
                float z = rintf(__fmul_rn(t, 2.f));
                z = fminf(fmaxf(z, -2.f), 1.f);
                v[r] = __fmul_rn(z, 0.5f);
            }
            *(f32x4*)(&out[(((size_t)(b * 256 + co)) * 32 + h) * 32 + w]) = v;
        }
    }
#undef LOAD_B
#undef LOAD_A
#undef MFMA
}

extern "C" void kernel_launch(void* const* d_in, const int* in_sizes, int n_in,
                              void* d_out, int out_size, void* d_ws, size_t ws_size,
                              hipStream_t stream) {
    const float* x      = (const float*)d_in[0];
    const float* weight = (const float*)d_in[1];
    const float* gamma  = (const float*)d_in[2];
    const float* beta   = (const float*)d_in[3];
    const float* rmean  = (const float*)d_in[4];
    const float* rvar   = (const float*)d_in[5];
    float* out = (float*)d_out;

    signed char* wq   = (signed char*)d_ws;                 // 589,824 B (MFMA layout)
    signed char* xpad = (signed char*)d_ws + (1 << 20);     // 9,469,952 B

    quant_kernel<<<1344, 256, 0, stream>>>(x, weight, xpad, wq);
    conv_gemm_kernel<<<256, 512, 0, stream>>>(xpad, wq, gamma, beta, rmean, rvar, out);
}

// Round 5
// 113.333 us; speedup vs baseline: 1.1222x; 1.1222x over previous
//
#include <hip/hip_runtime.h>
#include <hip/hip_bf16.h>
#include <stdint.h>

// B=32, C=256, H=W=32, 3x3 conv pad 1 -> implicit GEMM in INT8.
// M = 32768 (b,h,w), N = 256 (co), K = 2304; k = (kh*3+kw)*256 + ci.
// Two dispatches: (1) merged quant kernel (x -> int8 padded NHWC; w -> ternary
// int8 in MFMA fragment order), (2) GEMM with A staged once per block (52KB
// halo in LDS, 1 barrier) and B streamed per-fragment from L2.
//
// R5 (on R3; R0 structure LOCKED: 128x128 block, 8 waves 2m x 4n, 4 waves/SIMD
// -- every occupancy cut in R1/R2/R4 regressed, GEMM is latency-bound):
//  - B prefetch distance 2 (bP triple buffer, +8 VGPR): shadow for the
//    ~200cyc L1/L2 B-load latency doubles 164->328 effective cycles.
//  - XCD-chunked block swizzle (bijective, 512=8x64): blocks sharing the same
//    A-halo (n0 pair + adjacent mt) co-locate on one XCD's L2 (~1.8MB working
//    set < 4MB), removing cross-XCD refetch latency.

typedef int i32x4 __attribute__((ext_vector_type(4)));
typedef float f32x4 __attribute__((ext_vector_type(4)));

__device__ __forceinline__ void gload_lds16(const void* g, const void* lds) {
    __builtin_amdgcn_global_load_lds(
        (const __attribute__((address_space(1))) unsigned int*)(uintptr_t)g,
        (__attribute__((address_space(3))) unsigned int*)(uintptr_t)lds,
        16, 0, 0);
}

// Merged quantization (R3 version, unchanged). Blocks 0..1087: x-row ->
// int8 padded NHWC [b][34][34][ci], borders zeroed. Blocks 1088..1343:
// weight channel co -> ternary int8, MFMA-fragment order
// B'[(co>>4)][kt][kq][co&15][j], elem = Wq[co][k=kt*64+kq*16+j].
__global__ __launch_bounds__(256) void quant_kernel(
    const float* __restrict__ x, const float* __restrict__ w,
    signed char* __restrict__ xpad, signed char* __restrict__ wq)
{
    __shared__ signed char tile[32 * 272];
    const int t = threadIdx.x;
    const int blk = blockIdx.x;

    if (blk >= 1088) {                        // ---- weight path ----
        const int co = blk - 1088;
        signed char* wt = tile;               // reuse as [khkw*256 + ci]
#pragma unroll
        for (int p = 0; p < 9; ++p) {
            const int idx = p * 256 + t;      // = ci*9 + khkw
            const float v = w[co * 2304 + idx];
            const int ci = idx / 9;
            const int khkw = idx - 9 * ci;
            const float q = fminf(fmaxf(rintf(v), -1.f), 1.f);
            wt[khkw * 256 + ci] = (signed char)(int)q;
        }
        __syncthreads();
        if (t < 144) {                        // t = kt*4 + kq
            const int kt = t >> 2, kq = t & 3;
            const uint4 v = *(const uint4*)(wt + t * 16);
            *(uint4*)(wq + ((size_t)((co >> 4) * 36 + kt) << 10) + kq * 256 + (co & 15) * 16) = v;
        }
        return;
    }

    // ---- x path ----
    const int b = blk / 34;
    const int hp = blk % 34;
    signed char* rowbase = xpad + (size_t)((b * 34 + hp) * 34) * 256;
    const uint4 z = {0u, 0u, 0u, 0u};
    if (hp == 0 || hp == 33) {                // whole padded row = zeros
        for (int i = t; i < 544; i += 256) *(uint4*)(rowbase + i * 16) = z;
        return;
    }
    const int h = hp - 1;
    const float* xb = x + ((size_t)(b * 256) * 32 + h) * 32;   // + ci*1024 + w

#pragma unroll
    for (int q2 = 0; q2 < 2; ++q2) {
        const int beta = q2 * 256 + t;
        const int cib = beta >> 3;            // 0..63  (ci0 = 4*cib)
        const int w4 = beta & 7;              // 0..7   (w = w4*4 .. +3)
        unsigned row[4];
#pragma unroll
        for (int j = 0; j < 4; ++j) {
            const f32x4 v = *(const f32x4*)(xb + (size_t)(cib * 4 + j) * 1024 + w4 * 4);
            unsigned p = 0;
#pragma unroll
            for (int k = 0; k < 4; ++k) {
                const float q = fminf(fmaxf(rintf(__fmul_rn(v[k], 128.f)), -128.f), 127.f);
                p |= ((unsigned)(unsigned char)(signed char)(int)q) << (8 * k);
            }
            row[j] = p;
        }
        const unsigned ab_lo = __builtin_amdgcn_perm(row[1], row[0], 0x05010400u);
        const unsigned ab_hi = __builtin_amdgcn_perm(row[1], row[0], 0x07030602u);
        const unsigned cd_lo = __builtin_amdgcn_perm(row[3], row[2], 0x05010400u);
        const unsigned cd_hi = __builtin_amdgcn_perm(row[3], row[2], 0x07030602u);
        unsigned col[4];
        col[0] = __builtin_amdgcn_perm(cd_lo, ab_lo, 0x05040100u);
        col[1] = __builtin_amdgcn_perm(cd_lo, ab_lo, 0x07060302u);
        col[2] = __builtin_amdgcn_perm(cd_hi, ab_hi, 0x05040100u);
        col[3] = __builtin_amdgcn_perm(cd_hi, ab_hi, 0x07060302u);
#pragma unroll
        for (int r = 0; r < 4; ++r)
            *(unsigned*)(tile + (w4 * 4 + r) * 272 + cib * 4) = col[r];
    }
    __syncthreads();
#pragma unroll
    for (int q = 0; q < 2; ++q) {             // interior: 16B/lane, coalesced
        const int wp = q * 16 + (t >> 4);
        const int ci16 = (t & 15) * 16;
        uint4 v = *(const uint4*)(tile + wp * 272 + ci16);
        *(uint4*)(rowbase + (size_t)(wp + 1) * 256 + ci16) = v;
    }
    if (t < 32) {                             // zero border cols wp=0,33
        const int wp = (t >> 4) * 33;
        *(uint4*)(rowbase + (size_t)wp * 256 + (t & 15) * 16) = z;
    }
}

// GEMM: grid 512 (256 m-tiles x 2 n-tiles), 512 threads = 8 waves (2m x 4n).
// Wave = 64m x 32n: 4 m-frags x 2 n-frags of 16x16x64 i8.
// LDS: A halo only, 6 rows x 34 wp x 256 ci = 52,224 B, xor-swizzled chunks.
__global__ __launch_bounds__(512, 4) void conv_gemm_kernel(
    const signed char* __restrict__ xpad, const signed char* __restrict__ wqm,
    const float* __restrict__ gamma, const float* __restrict__ beta,
    const float* __restrict__ mean, const float* __restrict__ var,
    float* __restrict__ out)
{
    __shared__ signed char As[6 * 34 * 256];   // [r=hh*34+wp][chunk ^ (r&15)][16]

    const int tid = threadIdx.x;
    const int wv = tid >> 6;
    const int lane = tid & 63;
    const int l16 = lane & 15;
    const int l4 = lane >> 4;

    // XCD-chunked bijective swizzle: bid = x mod 8 (same XCD) -> contiguous
    // work ids x*64..x*64+63. Pairs (same mt) + adjacent mt share one L2.
    const int bid = (int)blockIdx.x;
    const int swz = (bid & 7) * 64 + (bid >> 3);

    const int mt = swz >> 1;
    const int n0 = (swz & 1) * 128;
    const int b = mt >> 3;
    const int h0 = (mt & 7) * 4;
    const int wave_m = wv & 1;    // 2 waves over m (64 each)
    const int wave_n = wv >> 1;   // 4 waves over n (32 each)

    // ---- stage A halo once: padded rows h0..h0+5, all 34 wp, all 256 ci ----
    const signed char* xbase = xpad + (size_t)(b * 34 + h0) * 34 * 256;
#pragma unroll
    for (int p = 0; p < 7; ++p) {                // 51 wave-shots x 1KB = 52,224B
        const int i = p * 8 + wv;
        if (i < 51) {
            const int d = i * 64 + lane;
            const int r = d >> 4;
            const int c = d & 15;
            gload_lds16(xbase + r * 256 + ((c ^ (r & 15)) << 4), As + i * 1024);
        }
    }
    __syncthreads();   // the ONLY barrier

    int r0[4];
#pragma unroll
    for (int i = 0; i < 4; ++i)
        r0[i] = (wave_m * 2 + (i >> 1)) * 34 + (i & 1) * 16 + l16;

    const signed char* bp0 = wqm + (((size_t)((n0 >> 4) + wave_n * 2 + 0) * 36) << 10) + lane * 16;
    const signed char* bp1 = wqm + (((size_t)((n0 >> 4) + wave_n * 2 + 1) * 36) << 10) + lane * 16;

    i32x4 acc[4][2];
#pragma unroll
    for (int i = 0; i < 4; i++)
#pragma unroll
        for (int j = 0; j < 2; j++) acc[i][j] = (i32x4){0, 0, 0, 0};

    i32x4 aP[2][4], bP[3][2];                    // B: distance-2 triple buffer

#define LOAD_B(kt, dst) { dst[0] = *(const i32x4*)(bp0 + (kt) * 1024); \
                          dst[1] = *(const i32x4*)(bp1 + (kt) * 1024); }
#define LOAD_A(kt, dst) { const int khkw = (kt) >> 2; \
                          const int kh = khkw / 3; \
                          const int kw = khkw - 3 * kh; \
                          const int roff = kh * 34 + kw; \
                          const int cb = ((kt) & 3) * 4 + l4; \
                          _Pragma("unroll") \
                          for (int i = 0; i < 4; ++i) { \
                              const int r = r0[i] + roff; \
                              dst[i] = *(const i32x4*)(As + r * 256 + ((cb ^ (r & 15)) << 4)); \
                          } }
#define MFMA(af, bf) { _Pragma("unroll") \
                       for (int i = 0; i < 4; ++i) \
                           _Pragma("unroll") \
                           for (int j = 0; j < 2; ++j) \
                               acc[i][j] = __builtin_amdgcn_mfma_i32_16x16x64_i8(af[i], bf[j], acc[i][j], 0, 0, 0); }

    LOAD_B(0, bP[0])
    LOAD_B(1, bP[1])
    LOAD_A(0, aP[0])
#pragma unroll
    for (int kt = 0; kt < 36; ++kt) {            // full unroll: offsets fold
        if (kt + 2 < 36) { LOAD_B(kt + 2, bP[(kt + 2) % 3]) }
        if (kt + 1 < 36) { LOAD_A(kt + 1, aP[(kt + 1) & 1]) }
        MFMA(aP[kt & 1], bP[kt % 3])
    }

    // ---- epilogue: C/D col = l16 (n), row = l4*4 + r (m within frag) ----
#pragma unroll
    for (int j = 0; j < 2; ++j) {
        const int co = n0 + wave_n * 32 + j * 16 + l16;
        const float iv = __fdiv_rn(gamma[co], __fsqrt_rn(__fadd_rn(var[co], 1e-4f)));
        const float bias = __fsub_rn(beta[co], __fmul_rn(mean[co], iv));
#pragma unroll
        for (int i = 0; i < 4; ++i) {
            const int h = h0 + wave_m * 2 + (i >> 1);
            const int w = (i & 1) * 16 + l4 * 4;
            f32x4 v;
#pragma unroll
            for (int r = 0; r < 4; r++) {
                const float y = __fmul_rn((float)acc[i][j][r], 0.0078125f);  // exact pow2
                const float t = __fadd_rn(__fmul_rn(y, iv), bias);           // no FMA: match np
                float z = rintf(__fmul_rn(t, 2.f));
                z = fminf(fmaxf(z, -2.f), 1.f);
                v[r] = __fmul_rn(z, 0.5f);
            }
            *(f32x4*)(&out[(((size_t)(b * 256 + co)) * 32 + h) * 32 + w]) = v;
        }
    }
#undef LOAD_B
#undef LOAD_A
#undef MFMA
}

extern "C" void kernel_launch(void* const* d_in, const int* in_sizes, int n_in,
                              void* d_out, int out_size, void* d_ws, size_t ws_size,
                              hipStream_t stream) {
    const float* x      = (const float*)d_in[0];
    const float* weight = (const float*)d_in[1];
    const float* gamma  = (const float*)d_in[2];
    const float* beta   = (const float*)d_in[3];
    const float* rmean  = (const float*)d_in[4];
    const float* rvar   = (const float*)d_in[5];
    float* out = (float*)d_out;

    signed char* wq   = (signed char*)d_ws;                 // 589,824 B (MFMA layout)
    signed char* xpad = (signed char*)d_ws + (1 << 20);     // 9,469,952 B

    quant_kernel<<<1344, 256, 0, stream>>>(x, weight, xpad, wq);
    conv_gemm_kernel<<<512, 512, 0, stream>>>(xpad, wq, gamma, beta, rmean, rvar, out);
}